// Round 14
// baseline (256.604 us; speedup 1.0000x reference)
//
#include <hip/hip_runtime.h>
#include <hip/hip_bf16.h>

namespace {
constexpr int Bn = 128, Cn = 2048, Nn = 196, Sn = 312, Ln = 300, Mn = 1024;
constexpr int Sp = 320, Lp = 320, PR = 192;

// f32-unit workspace offsets (all multiples of 4 f32 = 16 B)
constexpr size_t OFF_F16   = 0;                                  // fT fp16 TILED [(b*32+t)*196+n][64]
constexpr size_t OFF_POOLX = OFF_F16   + (size_t)Bn*Nn*Cn/2;     // fp16 [PR][Cn]
constexpr size_t OFF_HC    = OFF_POOLX + (size_t)PR*Cn/2;        // fp16 [Cn][Lp]
constexpr size_t OFF_WVM   = OFF_HC    + (size_t)Cn*Lp/2;        // fp16 [Sp][Mn]
constexpr size_t OFF_V16   = OFF_WVM   + (size_t)Sp*Mn/2;        // fp16 [Sp][Cn]
constexpr size_t OFF_WV16  = OFF_V16   + (size_t)Sp*Cn/2;        // fp16 [Cn][Mn]
constexpr size_t OFF_W2V   = OFF_WV16  + (size_t)Cn*Mn/2;        // fp16 [Sp][Lp]
constexpr size_t OFF_BQK   = OFF_W2V   + (size_t)Sp*Lp/2;        // f32 [Cn]
constexpr size_t OFF_QK    = OFF_BQK   + Cn;                     // fp16 [Sp][Cn]
constexpr size_t OFF_WWT   = OFF_QK    + (size_t)Sp*Cn/2;        // fp16 [Sp][Cn]
constexpr size_t OFF_PVF   = OFF_WWT   + (size_t)Sp*Cn/2;        // f32 [PR][Sp]
}

typedef __attribute__((ext_vector_type(8))) short u16x8;
typedef __attribute__((ext_vector_type(8))) _Float16 f16x8;
typedef __attribute__((ext_vector_type(4))) _Float16 f16x4;
typedef __attribute__((ext_vector_type(4))) float f32x4;

__device__ __forceinline__ f16x8 as_h(u16x8 v) { return __builtin_bit_cast(f16x8, v); }

__device__ __forceinline__ void gload16(void* lds, const void* g) {
    __builtin_amdgcn_global_load_lds(
        (const __attribute__((address_space(1))) void*)g,
        (__attribute__((address_space(3))) void*)lds, 16, 0, 0);
}

// Stage a [rows x 32] fp16 tile; XOR swizzle on SOURCE address so the matching
// swizzled frag_ld reads are conflict-free.
__device__ __forceinline__ void stage_rows(ushort* lds, const ushort* src,
                                           size_t row0, int k0, int ld,
                                           int tid, int nslots) {
    int base = 0;
    for (; base + 256 <= nslots; base += 256) {
        const int slot = base + tid;
        const int r = slot >> 2, q = (slot & 3) ^ ((r >> 1) & 3);
        gload16(lds + (size_t)(base + (tid & 192)) * 8,
                src + (row0 + r) * (size_t)ld + k0 + q * 8);
    }
    const int rem = nslots - base;
    if (rem && tid < rem) {
        const int slot = base + tid;
        const int r = slot >> 2, q = (slot & 3) ^ ((r >> 1) & 3);
        gload16(lds + (size_t)base * 8,
                src + (row0 + r) * (size_t)ld + k0 + q * 8);
    }
}

// read one 16x32 fragment (lane l: row = fr*16 + (l&15), k-chunk = l>>4)
__device__ __forceinline__ u16x8 frag_ld(const ushort* tile, int fr, int lane) {
    const int rl = lane & 15;
    const int q  = (lane >> 4) ^ ((rl >> 1) & 3);
    return *(const u16x8*)(tile + ((fr * 16 + rl) * 32 + q * 8));
}

// ---- mini GEMM, fp16 inputs via global_load_lds ----
__device__ __forceinline__ void mini16(
        const ushort* __restrict__ A, int lda, const ushort* __restrict__ B, int ldb,
        int r0, int c0, int K, const float* __restrict__ bias,
        _Float16* __restrict__ outh, float* __restrict__ outf, int ldo,
        ushort* sA, ushort* sB, int tid) {
    const int lane = tid & 63, wid = tid >> 6;
    f32x4 acc[2][2];
    #pragma unroll
    for (int i = 0; i < 2; ++i)
        #pragma unroll
        for (int j = 0; j < 2; ++j) acc[i][j] = (f32x4)0.f;
    const int fa = (wid >> 1) * 2, fb = (wid & 1) * 2;
    for (int k0 = 0; k0 < K; k0 += 32) {
        stage_rows(sA, A, r0, k0, lda, tid, 256);
        stage_rows(sB, B, c0, k0, ldb, tid, 256);
        __syncthreads();
        f16x8 a0 = as_h(frag_ld(sA, fa, lane)), a1 = as_h(frag_ld(sA, fa + 1, lane));
        f16x8 b0 = as_h(frag_ld(sB, fb, lane)), b1 = as_h(frag_ld(sB, fb + 1, lane));
        acc[0][0] = __builtin_amdgcn_mfma_f32_16x16x32_f16(a0, b0, acc[0][0], 0, 0, 0);
        acc[0][1] = __builtin_amdgcn_mfma_f32_16x16x32_f16(a0, b1, acc[0][1], 0, 0, 0);
        acc[1][0] = __builtin_amdgcn_mfma_f32_16x16x32_f16(a1, b0, acc[1][0], 0, 0, 0);
        acc[1][1] = __builtin_amdgcn_mfma_f32_16x16x32_f16(a1, b1, acc[1][1], 0, 0, 0);
        __syncthreads();
    }
    #pragma unroll
    for (int i = 0; i < 2; ++i)
        #pragma unroll
        for (int j = 0; j < 2; ++j)
            #pragma unroll
            for (int rr = 0; rr < 4; ++rr) {
                const size_t row = r0 + (wid >> 1) * 32 + i * 16 + (lane >> 4) * 4 + rr;
                const int col = c0 + (wid & 1) * 32 + j * 16 + (lane & 15);
                const float v = acc[i][j][rr] + (bias ? bias[col] : 0.f);
                if (outh) outh[row * ldo + col] = (_Float16)v;
                else      outf[row * ldo + col] = v;
            }
}

// ---- mini GEMM, f32 inputs with inline fp16 convert ----
__device__ __forceinline__ void mini_f32in(
        const float* __restrict__ A, int lda, int RA,
        const float* __restrict__ B, int ldb, int RB,
        int r0, int c0, int K, _Float16* __restrict__ out, int ldo,
        ushort* sA, ushort* sB, int tid) {
    const int lane = tid & 63, wid = tid >> 6;
    f32x4 acc[2][2];
    #pragma unroll
    for (int i = 0; i < 2; ++i)
        #pragma unroll
        for (int j = 0; j < 2; ++j) acc[i][j] = (f32x4)0.f;
    const int fa = (wid >> 1) * 2, fb = (wid & 1) * 2;
    for (int k0 = 0; k0 < K; k0 += 32) {
        #pragma unroll
        for (int p = 0; p < 2; ++p) {
            const int e = tid + p * 256;
            const int r = e >> 3, k4 = (e & 7) * 4;
            const int ad = r * 32 + (((k4 >> 3) ^ ((r >> 1) & 3)) << 3) + (k4 & 7);
            float4 va = (r0 + r < RA) ? *(const float4*)&A[(size_t)(r0 + r) * lda + k0 + k4]
                                      : make_float4(0.f, 0.f, 0.f, 0.f);
            f16x4 ha;
            ha[0] = (_Float16)va.x; ha[1] = (_Float16)va.y;
            ha[2] = (_Float16)va.z; ha[3] = (_Float16)va.w;
            *(f16x4*)&sA[ad] = ha;
            float4 vb = (c0 + r < RB) ? *(const float4*)&B[(size_t)(c0 + r) * ldb + k0 + k4]
                                      : make_float4(0.f, 0.f, 0.f, 0.f);
            f16x4 hb;
            hb[0] = (_Float16)vb.x; hb[1] = (_Float16)vb.y;
            hb[2] = (_Float16)vb.z; hb[3] = (_Float16)vb.w;
            *(f16x4*)&sB[ad] = hb;
        }
        __syncthreads();
        f16x8 a0 = as_h(frag_ld(sA, fa, lane)), a1 = as_h(frag_ld(sA, fa + 1, lane));
        f16x8 b0 = as_h(frag_ld(sB, fb, lane)), b1 = as_h(frag_ld(sB, fb + 1, lane));
        acc[0][0] = __builtin_amdgcn_mfma_f32_16x16x32_f16(a0, b0, acc[0][0], 0, 0, 0);
        acc[0][1] = __builtin_amdgcn_mfma_f32_16x16x32_f16(a0, b1, acc[0][1], 0, 0, 0);
        acc[1][0] = __builtin_amdgcn_mfma_f32_16x16x32_f16(a1, b0, acc[1][0], 0, 0, 0);
        acc[1][1] = __builtin_amdgcn_mfma_f32_16x16x32_f16(a1, b1, acc[1][1], 0, 0, 0);
        __syncthreads();
    }
    #pragma unroll
    for (int i = 0; i < 2; ++i)
        #pragma unroll
        for (int j = 0; j < 2; ++j)
            #pragma unroll
            for (int rr = 0; rr < 4; ++rr) {
                const size_t row = r0 + (wid >> 1) * 32 + i * 16 + (lane >> 4) * 4 + rr;
                const int col = c0 + (wid & 1) * 32 + j * 16 + (lane & 15);
                out[row * ldo + col] = (_Float16)acc[i][j][rr];
            }
}

// ================= STAGE A =================
// bvo(8) | Hc(160) | WV(80) | bqk(512) | prep(4096) | cvtV(640) | cvtWv(2048) | cvtW2v(100)
__global__ __launch_bounds__(256) void k_stageA(
        const float* __restrict__ feat, const float* __restrict__ w2v,
        const float* __restrict__ Wq,  const float* __restrict__ bq,
        const float* __restrict__ Wk,  const float* __restrict__ Wv,
        const float* __restrict__ bv,  const float* __restrict__ Wo,
        const float* __restrict__ bo,  const float* __restrict__ Vf,
        _Float16* __restrict__ f16, _Float16* __restrict__ poolx,
        _Float16* __restrict__ hc, _Float16* __restrict__ wvm,
        _Float16* __restrict__ v16, _Float16* __restrict__ wv16,
        _Float16* __restrict__ w2v16, float* __restrict__ bqk) {
    __shared__ __align__(16) char smem[28224];   // prep T: 196*9*16 B; minis: 8 KB
    const int tid = threadIdx.x;
    int i = blockIdx.x;
    if (i < 8) {
        const int c = i * 256 + tid;
        float acc = bo[c];
        #pragma unroll 8
        for (int m = 0; m < Mn; ++m) acc = fmaf(bv[m], Wo[(size_t)m * Cn + c], acc);
        poolx[(size_t)128 * Cn + c] = (_Float16)acc;
    } else if ((i -= 8) < 160) {
        ushort* sA = (ushort*)smem;
        mini_f32in(Wk, Mn, 1 << 30, Wq, Mn, Ln,
                   (i / 5) * 64, (i % 5) * 64, Mn, hc, Lp, sA, sA + 2048, tid);
    } else if ((i -= 160) < 80) {
        ushort* sA = (ushort*)smem;
        mini_f32in(Vf, Cn, Sn, Wo, Cn, 1 << 30,
                   (i / 16) * 64, (i % 16) * 64, Cn, wvm, Mn, sA, sA + 2048, tid);
    } else if ((i -= 80) < 512) {
        const int lane = tid & 63;
        const int c = i * 4 + (tid >> 6);
        float acc = 0.f;
        for (int m = lane; m < Mn; m += 64) acc = fmaf(bq[m], Wk[(size_t)c * Mn + m], acc);
        #pragma unroll
        for (int mm = 32; mm; mm >>= 1) acc += __shfl_xor(acc, mm);
        if (lane == 0) bqk[c] = acc;
    } else if ((i -= 512) < 4096) {
        // ===== prep v4: feat[b][c][n] -> TILED f16t[(b*32+t)*196+n][64] + poolx =====
        // T: [196 n][9 units of 16B] chunk-swizzled; in-reg 8x4 transpose; writes
        // are now one CONTIGUOUS 25 KB stream per block (1 KB per wave-op).
        ushort* T = (ushort*)smem;
        const int b = i >> 5, c0 = (i & 31) * 64;
        const float* fb = feat + ((size_t)b * Cn + c0) * Nn;
        for (int u = tid; u < 392; u += 256) {
            const int nq = u % 49, c8 = u / 49;
            float4 v[8];
            #pragma unroll
            for (int j = 0; j < 8; ++j)
                v[j] = *(const float4*)&fb[(size_t)(c8 * 8 + j) * Nn + nq * 4];
            const int x = c8 ^ (nq & 7);
            #pragma unroll
            for (int k = 0; k < 4; ++k) {
                f16x8 h;
                #pragma unroll
                for (int j = 0; j < 8; ++j)
                    h[j] = (_Float16)(((const float*)&v[j])[k]);
                *(f16x8*)&T[((nq * 4 + k) * 9 + x) * 8] = h;
            }
        }
        __syncthreads();
        // phase2: CONTIGUOUS write-out of the [196][64] tile (u*8 = n*64 + c8*8)
        ushort* outb = (ushort*)f16 + ((size_t)(b * 32) + (c0 >> 6)) * (196 * 64);
        for (int u = tid; u < 1568; u += 256) {
            const int n = u >> 3, c8 = u & 7;
            const int x = c8 ^ ((n >> 2) & 7);
            u16x8 h = *(const u16x8*)&T[(n * 9 + x) * 8];
            *(u16x8*)(outb + (size_t)u * 8) = h;
        }
        // phase3: pool from T (4 threads per c, 49 n each, shuffle-combine)
        {
            const int c = tid >> 2, q = tid & 3;
            float s = 0.f;
            for (int it = 0; it < 49; ++it) {
                const int n = q * 49 + it;
                const int x = (c >> 3) ^ ((n >> 2) & 7);
                s += (float)*(const _Float16*)&T[(n * 9 + x) * 8 + (c & 7)];
            }
            s += __shfl_xor(s, 1);
            s += __shfl_xor(s, 2);
            if (q == 0)
                poolx[(size_t)b * Cn + c0 + c] = (_Float16)(s * (1.0f / Nn));
        }
    } else if ((i -= 4096) < 640) {
        const size_t idx = ((size_t)i * 256 + tid) * 4;
        const int r = (int)(idx >> 11);
        float4 v = (r < Sn) ? *(const float4*)&Vf[idx] : make_float4(0.f, 0.f, 0.f, 0.f);
        f16x4 h;
        h[0] = (_Float16)v.x; h[1] = (_Float16)v.y; h[2] = (_Float16)v.z; h[3] = (_Float16)v.w;
        *(f16x4*)&v16[idx] = h;
    } else if ((i -= 640) < 2048) {
        const size_t idx = ((size_t)i * 256 + tid) * 4;
        const float4 v = *(const float4*)&Wv[idx];
        f16x4 h;
        h[0] = (_Float16)v.x; h[1] = (_Float16)v.y; h[2] = (_Float16)v.z; h[3] = (_Float16)v.w;
        *(f16x4*)&wv16[idx] = h;
    } else {
        i -= 2048;
        const int e0 = (i * 256 + tid) * 4;
        #pragma unroll
        for (int k = 0; k < 4; ++k) {
            const int e = e0 + k;
            const int r = e / Lp, cl = e - r * Lp;
            w2v16[e] = (r < Sn && cl < Ln) ? (_Float16)w2v[(size_t)r * Ln + cl] : (_Float16)0.f;
        }
    }
}

// ================= STAGE B: pv(15) | WWt(160) | qk(160) =================
__global__ __launch_bounds__(256) void k_stageB(
        const ushort* __restrict__ w2v16, const ushort* __restrict__ hc,
        const float* __restrict__ bqk, const ushort* __restrict__ wvm,
        const ushort* __restrict__ wv16, const ushort* __restrict__ poolx,
        const ushort* __restrict__ v16,
        _Float16* __restrict__ qk16, _Float16* __restrict__ wwt16,
        float* __restrict__ pvf) {
    __shared__ __align__(16) ushort sA[2048], sB[2048];
    const int tid = threadIdx.x;
    int i = blockIdx.x;
    if (i < 15) {
        mini16(poolx, Cn, v16, Cn, (i / 5) * 64, (i % 5) * 64, Cn,
               nullptr, nullptr, pvf, Sp, sA, sB, tid);
    } else if ((i -= 15) < 160) {
        mini16(wvm, Mn, wv16, Mn, (i / 32) * 64, (i % 32) * 64, Mn,
               nullptr, wwt16, nullptr, Cn, sA, sB, tid);
    } else {
        i -= 160;
        mini16(w2v16, Lp, hc, Lp, (i / 32) * 64, (i % 32) * 64, Lp,
               bqk, qk16, nullptr, Cn, sA, sB, tid);
    }
}

// ====== fused attention: tiled-F gather, double-buffered, __syncthreads-safe ======
__global__ __launch_bounds__(256) void k_attn(
        const _Float16* __restrict__ f16, const _Float16* __restrict__ qk16,
        const _Float16* __restrict__ ww16, const float* __restrict__ pvf,
        float* __restrict__ out) {
    __shared__ __align__(16) ushort smem[2][10752];   // per buf: F 6656 | Q 2048 | W 2048
    const int tid = threadIdx.x, lane = tid & 63, wid = tid >> 6;
    const int id = blockIdx.x;
    const int xcd = id & 7, slot0 = id >> 3;
    const int b  = xcd * 16 + slot0 / 5;   // 5 sibling s-tiles -> same XCD
    const int s0 = (slot0 % 5) * 64;

    f32x4 sc[13], vw[13];
    #pragma unroll
    for (int j = 0; j < 13; ++j) { sc[j] = (f32x4)0.f; vw[j] = (f32x4)0.f; }

    auto stage3 = [&](int p, int k0) {
        ushort* s = smem[p];
        // F from tiled layout: rows 128 B apart inside one 25 KB tile (L2-hot)
        const ushort* fbase = (const ushort*)f16 +
            ((size_t)(b * 32) + (k0 >> 6)) * (196 * 64) + ((k0 >> 5) & 1) * 32;
        int base = 0;
        for (; base + 256 <= 832; base += 256) {
            const int sl = base + tid;
            const int r = sl >> 2, q = (sl & 3) ^ ((r >> 1) & 3);
            const int rc = r < 196 ? r : 195;     // pad rows (masked later)
            gload16(s + (size_t)(base + (tid & 192)) * 8, fbase + rc * 64 + q * 8);
        }
        if (tid < 64) {
            const int sl = base + tid;
            const int r = sl >> 2, q = (sl & 3) ^ ((r >> 1) & 3);
            const int rc = r < 196 ? r : 195;
            gload16(s + (size_t)base * 8, fbase + rc * 64 + q * 8);
        }
        stage_rows(s + 6656, (const ushort*)qk16, s0, k0, Cn, tid, 256);
        stage_rows(s + 8704, (const ushort*)ww16, s0, k0, Cn, tid, 256);
    };

    constexpr int NIT = Cn / 32;
    stage3(0, 0);
    for (int t = 0; t < NIT; ++t) {
        const int cur = t & 1;
        __syncthreads();
        if (t + 1 < NIT) stage3(cur ^ 1, (t + 1) * 32);
        const ushort* sF = smem[cur];
        const f16x8 qf = as_h(frag_ld(sF + 6656, wid, lane));
        const f16x8 wf = as_h(frag_ld(sF + 8704, wid, lane));
        #pragma unroll
        for (int j = 0; j < 13; ++j) {
            const f16x8 ff = as_h(frag_ld(sF, j, lane));
            sc[j] = __builtin_amdgcn_mfma_f32_16x16x32_f16(qf, ff, sc[j], 0, 0, 0);
            vw[j] = __builtin_amdgcn_mfma_f32_16x16x32_f16(wf, ff, vw[j], 0, 0, 0);
        }
    }

    const int g = lane & 15;
    #pragma unroll
    for (int rr = 0; rr < 4; ++rr) {
        float mx = -1e30f;
        #pragma unroll
        for (int j = 0; j < 13; ++j)
            if (j < 12 || g < 4) mx = fmaxf(mx, sc[j][rr]);
        #pragma unroll
        for (int mm = 1; mm < 16; mm <<= 1) mx = fmaxf(mx, __shfl_xor(mx, mm));
        float den = 0.f, num = 0.f;
        #pragma unroll
        for (int j = 0; j < 13; ++j)
            if (j < 12 || g < 4) {
                const float e = __expf(sc[j][rr] - mx);
                den += e;
                num = fmaf(e, vw[j][rr], num);
            }
        #pragma unroll
        for (int mm = 1; mm < 16; mm <<= 1) {
            den += __shfl_xor(den, mm);
            num += __shfl_xor(num, mm);
        }
        if (g == 0) {
            const int s = s0 + wid * 16 + (lane >> 4) * 4 + rr;
            if (s < Sn)
                out[(size_t)b * Sn + s] =
                    pvf[(size_t)b * Sp + s] + pvf[(size_t)128 * Sp + s] + num / den;
        }
    }
}

extern "C" void kernel_launch(void* const* d_in, const int* in_sizes, int n_in,
                              void* d_out, int out_size, void* d_ws, size_t ws_size,
                              hipStream_t stream) {
    (void)in_sizes; (void)n_in; (void)ws_size; (void)out_size;
    const float* feat = (const float*)d_in[0];
    const float* w2v  = (const float*)d_in[1];
    const float* Wq   = (const float*)d_in[2];
    const float* bq   = (const float*)d_in[3];
    const float* Wk   = (const float*)d_in[4];
    const float* Wv   = (const float*)d_in[6];
    const float* bv   = (const float*)d_in[7];
    const float* Wo   = (const float*)d_in[8];
    const float* bo   = (const float*)d_in[9];
    const float* Vf   = (const float*)d_in[10];
    float* out = (float*)d_out;
    float* ws  = (float*)d_ws;

    _Float16* f16   = (_Float16*)(ws + OFF_F16);
    _Float16* poolx = (_Float16*)(ws + OFF_POOLX);
    _Float16* hc    = (_Float16*)(ws + OFF_HC);
    _Float16* wvm   = (_Float16*)(ws + OFF_WVM);
    _Float16* v16   = (_Float16*)(ws + OFF_V16);
    _Float16* wv16  = (_Float16*)(ws + OFF_WV16);
    _Float16* w2v16 = (_Float16*)(ws + OFF_W2V);
    float*    bqk   = ws + OFF_BQK;
    _Float16* qk16  = (_Float16*)(ws + OFF_QK);
    _Float16* wwt16 = (_Float16*)(ws + OFF_WWT);
    float*    pvf   = ws + OFF_PVF;

    k_stageA<<<dim3(8 + 160 + 80 + 512 + 4096 + 640 + 2048 + 100), 256, 0, stream>>>(
        feat, w2v, Wq, bq, Wk, Wv, bv, Wo, bo, Vf,
        f16, poolx, hc, wvm, v16, wv16, w2v16, bqk);
    k_stageB<<<dim3(15 + 160 + 160), 256, 0, stream>>>(
        (const ushort*)w2v16, (const ushort*)hc, bqk, (const ushort*)wvm,
        (const ushort*)wv16, (const ushort*)poolx, (const ushort*)v16,
        qk16, wwt16, pvf);
    k_attn<<<dim3(640), 256, 0, stream>>>(f16, qk16, wwt16, pvf, out);
}

// Round 15
// 215.910 us; speedup vs baseline: 1.1885x; 1.1885x over previous
//
#include <hip/hip_runtime.h>
#include <hip/hip_bf16.h>

namespace {
constexpr int Bn = 128, Cn = 2048, Nn = 196, Sn = 312, Ln = 300, Mn = 1024;
constexpr int Sp = 320, Lp = 320, PR = 192;

// f32-unit workspace offsets (all multiples of 4 f32 = 16 B)
constexpr size_t OFF_F16   = 0;                                  // fT fp16 TILED [(b*32+t)*196+n][64]
constexpr size_t OFF_POOLX = OFF_F16   + (size_t)Bn*Nn*Cn/2;     // fp16 [PR][Cn]
constexpr size_t OFF_HC    = OFF_POOLX + (size_t)PR*Cn/2;        // fp16 [Cn][Lp]
constexpr size_t OFF_WVM   = OFF_HC    + (size_t)Cn*Lp/2;        // fp16 [Sp][Mn]
constexpr size_t OFF_V16   = OFF_WVM   + (size_t)Sp*Mn/2;        // fp16 [Sp][Cn]
constexpr size_t OFF_WV16  = OFF_V16   + (size_t)Sp*Cn/2;        // fp16 [Cn][Mn]
constexpr size_t OFF_W2V   = OFF_WV16  + (size_t)Cn*Mn/2;        // fp16 [Sp][Lp]
constexpr size_t OFF_BQK   = OFF_W2V   + (size_t)Sp*Lp/2;        // f32 [Cn]
constexpr size_t OFF_QK    = OFF_BQK   + Cn;                     // fp16 [Sp][Cn]
constexpr size_t OFF_WWT   = OFF_QK    + (size_t)Sp*Cn/2;        // fp16 [Sp][Cn]
constexpr size_t OFF_PVF   = OFF_WWT   + (size_t)Sp*Cn/2;        // f32 [PR][Sp]
}

typedef __attribute__((ext_vector_type(8))) short u16x8;
typedef __attribute__((ext_vector_type(8))) _Float16 f16x8;
typedef __attribute__((ext_vector_type(4))) _Float16 f16x4;
typedef __attribute__((ext_vector_type(4))) float f32x4;

__device__ __forceinline__ f16x8 as_h(u16x8 v) { return __builtin_bit_cast(f16x8, v); }

__device__ __forceinline__ void gload16(void* lds, const void* g) {
    __builtin_amdgcn_global_load_lds(
        (const __attribute__((address_space(1))) void*)g,
        (__attribute__((address_space(3))) void*)lds, 16, 0, 0);
}

// Stage a [rows x 32] fp16 tile; XOR swizzle on SOURCE address so the matching
// swizzled frag_ld reads are conflict-free.
__device__ __forceinline__ void stage_rows(ushort* lds, const ushort* src,
                                           size_t row0, int k0, int ld,
                                           int tid, int nslots) {
    int base = 0;
    for (; base + 256 <= nslots; base += 256) {
        const int slot = base + tid;
        const int r = slot >> 2, q = (slot & 3) ^ ((r >> 1) & 3);
        gload16(lds + (size_t)(base + (tid & 192)) * 8,
                src + (row0 + r) * (size_t)ld + k0 + q * 8);
    }
    const int rem = nslots - base;
    if (rem && tid < rem) {
        const int slot = base + tid;
        const int r = slot >> 2, q = (slot & 3) ^ ((r >> 1) & 3);
        gload16(lds + (size_t)base * 8,
                src + (row0 + r) * (size_t)ld + k0 + q * 8);
    }
}

// read one 16x32 fragment (lane l: row = fr*16 + (l&15), k-chunk = l>>4)
__device__ __forceinline__ u16x8 frag_ld(const ushort* tile, int fr, int lane) {
    const int rl = lane & 15;
    const int q  = (lane >> 4) ^ ((rl >> 1) & 3);
    return *(const u16x8*)(tile + ((fr * 16 + rl) * 32 + q * 8));
}

// ---- mini GEMM, fp16 inputs, DOUBLE-BUFFERED gload_lds (k_attn-proven loop) ----
// sm: 8192 ushorts = 16 KB (2 bufs x (A 2048 | B 2048))
__device__ __forceinline__ void mini16(
        const ushort* __restrict__ A, int lda, const ushort* __restrict__ B, int ldb,
        int r0, int c0, int K, const float* __restrict__ bias,
        _Float16* __restrict__ outh, float* __restrict__ outf, int ldo,
        ushort* sm, int tid) {
    const int lane = tid & 63, wid = tid >> 6;
    f32x4 acc[2][2];
    #pragma unroll
    for (int i = 0; i < 2; ++i)
        #pragma unroll
        for (int j = 0; j < 2; ++j) acc[i][j] = (f32x4)0.f;
    const int fa = (wid >> 1) * 2, fb = (wid & 1) * 2;
    const int NI = K / 32;
    stage_rows(sm,        A, r0, 0, lda, tid, 256);
    stage_rows(sm + 2048, B, c0, 0, ldb, tid, 256);
    for (int t = 0; t < NI; ++t) {
        const int cur = (t & 1) * 4096;
        __syncthreads();                         // publishes buf[cur]
        if (t + 1 < NI) {
            stage_rows(sm + (cur ^ 4096),        A, r0, (t + 1) * 32, lda, tid, 256);
            stage_rows(sm + (cur ^ 4096) + 2048, B, c0, (t + 1) * 32, ldb, tid, 256);
        }
        const ushort* sA = sm + cur;
        const ushort* sB = sm + cur + 2048;
        f16x8 a0 = as_h(frag_ld(sA, fa, lane)), a1 = as_h(frag_ld(sA, fa + 1, lane));
        f16x8 b0 = as_h(frag_ld(sB, fb, lane)), b1 = as_h(frag_ld(sB, fb + 1, lane));
        acc[0][0] = __builtin_amdgcn_mfma_f32_16x16x32_f16(a0, b0, acc[0][0], 0, 0, 0);
        acc[0][1] = __builtin_amdgcn_mfma_f32_16x16x32_f16(a0, b1, acc[0][1], 0, 0, 0);
        acc[1][0] = __builtin_amdgcn_mfma_f32_16x16x32_f16(a1, b0, acc[1][0], 0, 0, 0);
        acc[1][1] = __builtin_amdgcn_mfma_f32_16x16x32_f16(a1, b1, acc[1][1], 0, 0, 0);
    }
    #pragma unroll
    for (int i = 0; i < 2; ++i)
        #pragma unroll
        for (int j = 0; j < 2; ++j)
            #pragma unroll
            for (int rr = 0; rr < 4; ++rr) {
                const size_t row = r0 + (wid >> 1) * 32 + i * 16 + (lane >> 4) * 4 + rr;
                const int col = c0 + (wid & 1) * 32 + j * 16 + (lane & 15);
                const float v = acc[i][j][rr] + (bias ? bias[col] : 0.f);
                if (outh) outh[row * ldo + col] = (_Float16)v;
                else      outf[row * ldo + col] = v;
            }
}

// ---- mini GEMM, f32 inputs, reg-prefetch-under-MFMA (T14; R11-verified pattern) ----
__device__ __forceinline__ void mini_f32in(
        const float* __restrict__ A, int lda, int RA,
        const float* __restrict__ B, int ldb, int RB,
        int r0, int c0, int K, _Float16* __restrict__ out, int ldo,
        ushort* sA, ushort* sB, int tid) {
    const int lane = tid & 63, wid = tid >> 6;
    f32x4 acc[2][2];
    #pragma unroll
    for (int i = 0; i < 2; ++i)
        #pragma unroll
        for (int j = 0; j < 2; ++j) acc[i][j] = (f32x4)0.f;
    const int fa = (wid >> 1) * 2, fb = (wid & 1) * 2;

    float4 va[2], vb[2];
    auto loadregs = [&](int k0) {
        #pragma unroll
        for (int p = 0; p < 2; ++p) {
            const int e = tid + p * 256;
            const int r = e >> 3, k4 = (e & 7) * 4;
            va[p] = (r0 + r < RA) ? *(const float4*)&A[(size_t)(r0 + r) * lda + k0 + k4]
                                  : make_float4(0.f, 0.f, 0.f, 0.f);
            vb[p] = (c0 + r < RB) ? *(const float4*)&B[(size_t)(c0 + r) * ldb + k0 + k4]
                                  : make_float4(0.f, 0.f, 0.f, 0.f);
        }
    };
    loadregs(0);
    for (int k0 = 0; k0 < K; k0 += 32) {
        #pragma unroll
        for (int p = 0; p < 2; ++p) {
            const int e = tid + p * 256;
            const int r = e >> 3, k4 = (e & 7) * 4;
            const int ad = r * 32 + (((k4 >> 3) ^ ((r >> 1) & 3)) << 3) + (k4 & 7);
            f16x4 ha;
            ha[0] = (_Float16)va[p].x; ha[1] = (_Float16)va[p].y;
            ha[2] = (_Float16)va[p].z; ha[3] = (_Float16)va[p].w;
            *(f16x4*)&sA[ad] = ha;
            f16x4 hb;
            hb[0] = (_Float16)vb[p].x; hb[1] = (_Float16)vb[p].y;
            hb[2] = (_Float16)vb[p].z; hb[3] = (_Float16)vb[p].w;
            *(f16x4*)&sB[ad] = hb;
        }
        __syncthreads();
        if (k0 + 32 < K) loadregs(k0 + 32);      // HBM latency hides under MFMA
        f16x8 a0 = as_h(frag_ld(sA, fa, lane)), a1 = as_h(frag_ld(sA, fa + 1, lane));
        f16x8 b0 = as_h(frag_ld(sB, fb, lane)), b1 = as_h(frag_ld(sB, fb + 1, lane));
        acc[0][0] = __builtin_amdgcn_mfma_f32_16x16x32_f16(a0, b0, acc[0][0], 0, 0, 0);
        acc[0][1] = __builtin_amdgcn_mfma_f32_16x16x32_f16(a0, b1, acc[0][1], 0, 0, 0);
        acc[1][0] = __builtin_amdgcn_mfma_f32_16x16x32_f16(a1, b0, acc[1][0], 0, 0, 0);
        acc[1][1] = __builtin_amdgcn_mfma_f32_16x16x32_f16(a1, b1, acc[1][1], 0, 0, 0);
        __syncthreads();                          // all reads done before next write
    }
    #pragma unroll
    for (int i = 0; i < 2; ++i)
        #pragma unroll
        for (int j = 0; j < 2; ++j)
            #pragma unroll
            for (int rr = 0; rr < 4; ++rr) {
                const size_t row = r0 + (wid >> 1) * 32 + i * 16 + (lane >> 4) * 4 + rr;
                const int col = c0 + (wid & 1) * 32 + j * 16 + (lane & 15);
                out[row * ldo + col] = (_Float16)acc[i][j][rr];
            }
}

// ================= STAGE A (R7 order; prep = R7 f32 tile + R13 tiled write) ======
// bvo(8) | bqk(512) | Hc(160) | WV(80) | cvtV(640) | cvtWv(2048) | cvtW2v(100) | prep(4096)
__global__ __launch_bounds__(256) void k_stageA(
        const float* __restrict__ feat, const float* __restrict__ w2v,
        const float* __restrict__ Wq,  const float* __restrict__ bq,
        const float* __restrict__ Wk,  const float* __restrict__ Wv,
        const float* __restrict__ bv,  const float* __restrict__ Wo,
        const float* __restrict__ bo,  const float* __restrict__ Vf,
        _Float16* __restrict__ f16, _Float16* __restrict__ poolx,
        _Float16* __restrict__ hc, _Float16* __restrict__ wvm,
        _Float16* __restrict__ v16, _Float16* __restrict__ wv16,
        _Float16* __restrict__ w2v16, float* __restrict__ bqk) {
    __shared__ __align__(16) char smem[51456];   // prep: 64*197*4 + 64*4*4; minis: 8 KB
    const int tid = threadIdx.x;
    int i = blockIdx.x;
    if (i < 8) {
        const int c = i * 256 + tid;
        float acc = bo[c];
        #pragma unroll 8
        for (int m = 0; m < Mn; ++m) acc = fmaf(bv[m], Wo[(size_t)m * Cn + c], acc);
        poolx[(size_t)128 * Cn + c] = (_Float16)acc;
    } else if ((i -= 8) < 512) {
        const int lane = tid & 63;
        const int c = i * 4 + (tid >> 6);
        float acc = 0.f;
        for (int m = lane; m < Mn; m += 64) acc = fmaf(bq[m], Wk[(size_t)c * Mn + m], acc);
        #pragma unroll
        for (int mm = 32; mm; mm >>= 1) acc += __shfl_xor(acc, mm);
        if (lane == 0) bqk[c] = acc;
    } else if ((i -= 512) < 160) {
        ushort* sA = (ushort*)smem;
        mini_f32in(Wk, Mn, 1 << 30, Wq, Mn, Ln,
                   (i / 5) * 64, (i % 5) * 64, Mn, hc, Lp, sA, sA + 2048, tid);
    } else if ((i -= 160) < 80) {
        ushort* sA = (ushort*)smem;
        mini_f32in(Vf, Cn, Sn, Wo, Cn, 1 << 30,
                   (i / 16) * 64, (i % 16) * 64, Cn, wvm, Mn, sA, sA + 2048, tid);
    } else if ((i -= 80) < 640) {
        const size_t idx = ((size_t)i * 256 + tid) * 4;
        const int r = (int)(idx >> 11);
        float4 v = (r < Sn) ? *(const float4*)&Vf[idx] : make_float4(0.f, 0.f, 0.f, 0.f);
        f16x4 h;
        h[0] = (_Float16)v.x; h[1] = (_Float16)v.y; h[2] = (_Float16)v.z; h[3] = (_Float16)v.w;
        *(f16x4*)&v16[idx] = h;
    } else if ((i -= 640) < 2048) {
        const size_t idx = ((size_t)i * 256 + tid) * 4;
        const float4 v = *(const float4*)&Wv[idx];
        f16x4 h;
        h[0] = (_Float16)v.x; h[1] = (_Float16)v.y; h[2] = (_Float16)v.z; h[3] = (_Float16)v.w;
        *(f16x4*)&wv16[idx] = h;
    } else if ((i -= 2048) < 100) {
        const int e0 = (i * 256 + tid) * 4;
        #pragma unroll
        for (int k = 0; k < 4; ++k) {
            const int e = e0 + k;
            const int r = e / Lp, cl = e - r * Lp;
            w2v16[e] = (r < Sn && cl < Ln) ? (_Float16)w2v[(size_t)r * Ln + cl] : (_Float16)0.f;
        }
    } else {
        // ===== prep (R7 f32 tile, fastest measured) -> TILED f16 output =====
        i -= 100;
        float (*t)[197] = (float(*)[197])smem;
        float (*pp)[4]  = (float(*)[4])(smem + 64 * 197 * 4);
        const int b = i >> 5, c0 = (i & 31) * 64;
        for (int idx = tid; idx < 64 * 49; idx += 256) {
            const int r = idx / 49, nq = idx - r * 49;
            const float4 v = *(const float4*)&feat[((size_t)b * Cn + c0 + r) * Nn + nq * 4];
            t[r][nq * 4 + 0] = v.x; t[r][nq * 4 + 1] = v.y;
            t[r][nq * 4 + 2] = v.z; t[r][nq * 4 + 3] = v.w;
        }
        __syncthreads();
        {   // pool partials: 4 threads per c, 49 n each
            const int c = tid >> 2, q = tid & 3;
            float s = 0.f;
            #pragma unroll
            for (int n = 0; n < 49; ++n) s += t[c][q * 49 + n];
            pp[c][q] = s;
        }
        // contiguous tiled write-out: f16t[(b*32 + c0/64)*196 + n][64]
        ushort* outb = (ushort*)f16 + ((size_t)(b * 32) + (c0 >> 6)) * (196 * 64);
        for (int idx = tid; idx < Nn * 32; idx += 256) {
            const int n = idx >> 5, cp = (idx & 31) * 2;
            f16x4 h;
            h[0] = (_Float16)t[cp][n]; h[1] = (_Float16)t[cp + 1][n];
            *(uint*)&outb[(size_t)n * 64 + cp] = *(uint*)&h;
        }
        __syncthreads();
        if (tid < 64)
            poolx[(size_t)b * Cn + c0 + tid] =
                (_Float16)((pp[tid][0] + pp[tid][1] + pp[tid][2] + pp[tid][3]) * (1.0f / Nn));
    }
}

// ================= STAGE B: pv(15) | WWt(160) | qk(160) — dbuf minis =================
__global__ __launch_bounds__(256) void k_stageB(
        const ushort* __restrict__ w2v16, const ushort* __restrict__ hc,
        const float* __restrict__ bqk, const ushort* __restrict__ wvm,
        const ushort* __restrict__ wv16, const ushort* __restrict__ poolx,
        const ushort* __restrict__ v16,
        _Float16* __restrict__ qk16, _Float16* __restrict__ wwt16,
        float* __restrict__ pvf) {
    __shared__ __align__(16) ushort sm[8192];   // 16 KB: 2 bufs x (A|B)
    const int tid = threadIdx.x;
    int i = blockIdx.x;
    if (i < 15) {
        mini16(poolx, Cn, v16, Cn, (i / 5) * 64, (i % 5) * 64, Cn,
               nullptr, nullptr, pvf, Sp, sm, tid);
    } else if ((i -= 15) < 160) {
        mini16(wvm, Mn, wv16, Mn, (i / 32) * 64, (i % 32) * 64, Mn,
               nullptr, wwt16, nullptr, Cn, sm, tid);
    } else {
        i -= 160;
        mini16(w2v16, Lp, hc, Lp, (i / 32) * 64, (i % 32) * 64, Lp,
               bqk, qk16, nullptr, Cn, sm, tid);
    }
}

// ====== fused attention: tiled-F gather, double-buffered (R13, proven) ======
__global__ __launch_bounds__(256) void k_attn(
        const _Float16* __restrict__ f16, const _Float16* __restrict__ qk16,
        const _Float16* __restrict__ ww16, const float* __restrict__ pvf,
        float* __restrict__ out) {
    __shared__ __align__(16) ushort smem[2][10752];   // per buf: F 6656 | Q 2048 | W 2048
    const int tid = threadIdx.x, lane = tid & 63, wid = tid >> 6;
    const int id = blockIdx.x;
    const int xcd = id & 7, slot0 = id >> 3;
    const int b  = xcd * 16 + slot0 / 5;   // 5 sibling s-tiles -> same XCD
    const int s0 = (slot0 % 5) * 64;

    f32x4 sc[13], vw[13];
    #pragma unroll
    for (int j = 0; j < 13; ++j) { sc[j] = (f32x4)0.f; vw[j] = (f32x4)0.f; }

    auto stage3 = [&](int p, int k0) {
        ushort* s = smem[p];
        const ushort* fbase = (const ushort*)f16 +
            ((size_t)(b * 32) + (k0 >> 6)) * (196 * 64) + ((k0 >> 5) & 1) * 32;
        int base = 0;
        for (; base + 256 <= 832; base += 256) {
            const int sl = base + tid;
            const int r = sl >> 2, q = (sl & 3) ^ ((r >> 1) & 3);
            const int rc = r < 196 ? r : 195;     // pad rows (masked later)
            gload16(s + (size_t)(base + (tid & 192)) * 8, fbase + rc * 64 + q * 8);
        }
        if (tid < 64) {
            const int sl = base + tid;
            const int r = sl >> 2, q = (sl & 3) ^ ((r >> 1) & 3);
            const int rc = r < 196 ? r : 195;
            gload16(s + (size_t)base * 8, fbase + rc * 64 + q * 8);
        }
        stage_rows(s + 6656, (const ushort*)qk16, s0, k0, Cn, tid, 256);
        stage_rows(s + 8704, (const ushort*)ww16, s0, k0, Cn, tid, 256);
    };

    constexpr int NIT = Cn / 32;
    stage3(0, 0);
    for (int t = 0; t < NIT; ++t) {
        const int cur = t & 1;
        __syncthreads();
        if (t + 1 < NIT) stage3(cur ^ 1, (t + 1) * 32);
        const ushort* sF = smem[cur];
        const f16x8 qf = as_h(frag_ld(sF + 6656, wid, lane));
        const f16x8 wf = as_h(frag_ld(sF + 8704, wid, lane));
        #pragma unroll
        for (int j = 0; j < 13; ++j) {
            const f16x8 ff = as_h(frag_ld(sF, j, lane));
            sc[j] = __builtin_amdgcn_mfma_f32_16x16x32_f16(qf, ff, sc[j], 0, 0, 0);
            vw[j] = __builtin_amdgcn_mfma_f32_16x16x32_f16(wf, ff, vw[j], 0, 0, 0);
        }
    }

    const int g = lane & 15;
    #pragma unroll
    for (int rr = 0; rr < 4; ++rr) {
        float mx = -1e30f;
        #pragma unroll
        for (int j = 0; j < 13; ++j)
            if (j < 12 || g < 4) mx = fmaxf(mx, sc[j][rr]);
        #pragma unroll
        for (int mm = 1; mm < 16; mm <<= 1) mx = fmaxf(mx, __shfl_xor(mx, mm));
        float den = 0.f, num = 0.f;
        #pragma unroll
        for (int j = 0; j < 13; ++j)
            if (j < 12 || g < 4) {
                const float e = __expf(sc[j][rr] - mx);
                den += e;
                num = fmaf(e, vw[j][rr], num);
            }
        #pragma unroll
        for (int mm = 1; mm < 16; mm <<= 1) {
            den += __shfl_xor(den, mm);
            num += __shfl_xor(num, mm);
        }
        if (g == 0) {
            const int s = s0 + wid * 16 + (lane >> 4) * 4 + rr;
            if (s < Sn)
                out[(size_t)b * Sn + s] =
                    pvf[(size_t)b * Sp + s] + pvf[(size_t)128 * Sp + s] + num / den;
        }
    }
}

extern "C" void kernel_launch(void* const* d_in, const int* in_sizes, int n_in,
                              void* d_out, int out_size, void* d_ws, size_t ws_size,
                              hipStream_t stream) {
    (void)in_sizes; (void)n_in; (void)ws_size; (void)out_size;
    const float* feat = (const float*)d_in[0];
    const float* w2v  = (const float*)d_in[1];
    const float* Wq   = (const float*)d_in[2];
    const float* bq   = (const float*)d_in[3];
    const float* Wk   = (const float*)d_in[4];
    const float* Wv   = (const float*)d_in[6];
    const float* bv   = (const float*)d_in[7];
    const float* Wo   = (const float*)d_in[8];
    const float* bo   = (const float*)d_in[9];
    const float* Vf   = (const float*)d_in[10];
    float* out = (float*)d_out;
    float* ws  = (float*)d_ws;

    _Float16* f16   = (_Float16*)(ws + OFF_F16);
    _Float16* poolx = (_Float16*)(ws + OFF_POOLX);
    _Float16* hc    = (_Float16*)(ws + OFF_HC);
    _Float16* wvm   = (_Float16*)(ws + OFF_WVM);
    _Float16* v16   = (_Float16*)(ws + OFF_V16);
    _Float16* wv16  = (_Float16*)(ws + OFF_WV16);
    _Float16* w2v16 = (_Float16*)(ws + OFF_W2V);
    float*    bqk   = ws + OFF_BQK;
    _Float16* qk16  = (_Float16*)(ws + OFF_QK);
    _Float16* wwt16 = (_Float16*)(ws + OFF_WWT);
    float*    pvf   = ws + OFF_PVF;

    k_stageA<<<dim3(8 + 512 + 160 + 80 + 640 + 2048 + 100 + 4096), 256, 0, stream>>>(
        feat, w2v, Wq, bq, Wk, Wv, bv, Wo, bo, Vf,
        f16, poolx, hc, wvm, v16, wv16, w2v16, bqk);
    k_stageB<<<dim3(15 + 160 + 160), 256, 0, stream>>>(
        (const ushort*)w2v16, (const ushort*)hc, bqk, (const ushort*)wvm,
        (const ushort*)wv16, (const ushort*)poolx, (const ushort*)v16,
        qk16, wwt16, pvf);
    k_attn<<<dim3(640), 256, 0, stream>>>(f16, qk16, wwt16, pvf, out);
}